// Round 8
// baseline (198.888 us; speedup 1.0000x reference)
//
#include <hip/hip_runtime.h>

#define LQ 768
#define DIN 256
#define DB 128
#define NH 8
#define DH 32

// ws float offsets
#define OFF_QB 0
#define OFF_KB (LQ*DIN)
#define OFF_VB (2*LQ*DIN)
#define OFF_GB (3*LQ*DIN)
#define OFF_W2 (4*LQ*DIN)
#define OFF_SC (OFF_W2 + DB*NH)
#define OFF_QK (OFF_SC + 16)              // qkT[q][k][h], 18.9 MB
#define OFF_LG (OFF_QK + LQ*LQ*NH)        // logits[q][k][h], 18.9 MB

// ---------------------------------------------------------------------------
// K1: proj (blocks 0..191, 4 rows each) + setup (block 192).
// ---------------------------------------------------------------------------
__global__ __launch_bounds__(256) void projsetup_kernel(
    const float* __restrict__ x, const float* __restrict__ lnw, const float* __restrict__ lnb,
    const float* __restrict__ Wq, const float* __restrict__ Wk, const float* __restrict__ Wv,
    const float* __restrict__ Wg, const float* __restrict__ bg,
    const float* __restrict__ lbw, const float* __restrict__ lbb, const float* __restrict__ Wb,
    float* __restrict__ qb, float* __restrict__ kb, float* __restrict__ vb, float* __restrict__ gb,
    float* __restrict__ W2, float* __restrict__ SC)
{
    const int tid = threadIdx.x;

    if (blockIdx.x == 192) {            // ---- setup ----
        if (tid < 128) {
            const int d = tid, lane = d & 63, wv = d >> 6;
            float w = lbw[d], b = lbb[d];
            float pS[NH], pC[NH];
            #pragma unroll
            for (int h = 0; h < NH; h++) {
                float wb = Wb[d*NH + h];
                float w2 = w * wb;
                W2[d*NH + h] = w2;
                pS[h] = w2;
                pC[h] = b * wb;
            }
            #pragma unroll
            for (int m = 1; m <= 32; m <<= 1) {
                #pragma unroll
                for (int h = 0; h < NH; h++) { pS[h] += __shfl_xor(pS[h], m); pC[h] += __shfl_xor(pC[h], m); }
            }
            __shared__ float red[2][16];
            if (lane == 0) {
                #pragma unroll
                for (int h = 0; h < NH; h++) { red[wv][h] = pS[h]; red[wv][NH+h] = pC[h]; }
            }
            __syncthreads();
            if (d < 16) SC[d] = red[0][d] + red[1][d];
        }
        return;
    }

    // ---- proj: 4 rows per block ----
    const int lane = tid & 63, rr = tid >> 6;
    const int row = blockIdx.x * 4 + rr;
    __shared__ float xn[4][DIN];

    float4 xv = ((const float4*)x)[row * (DIN/4) + lane];
    float s  = xv.x + xv.y + xv.z + xv.w;
    float ss = xv.x*xv.x + xv.y*xv.y + xv.z*xv.z + xv.w*xv.w;
    #pragma unroll
    for (int m = 1; m <= 32; m <<= 1) { s += __shfl_xor(s, m); ss += __shfl_xor(ss, m); }
    float mu  = s * (1.0f/DIN);
    float inv = rsqrtf(ss * (1.0f/DIN) - mu*mu + 1e-5f);
    float4 wv4 = ((const float4*)lnw)[lane];
    float4 bv4 = ((const float4*)lnb)[lane];
    float4 r4;
    r4.x = (xv.x - mu)*inv*wv4.x + bv4.x;
    r4.y = (xv.y - mu)*inv*wv4.y + bv4.y;
    r4.z = (xv.z - mu)*inv*wv4.z + bv4.z;
    r4.w = (xv.w - mu)*inv*wv4.w + bv4.w;
    *((float4*)&xn[rr][lane*4]) = r4;
    __syncthreads();

    const int col = tid;
    float aq[4] = {0,0,0,0}, ak[4] = {0,0,0,0}, av[4] = {0,0,0,0}, ag[4] = {0,0,0,0};
    for (int i4 = 0; i4 < DIN/4; i4++) {
        float4 x0 = *((const float4*)&xn[0][i4*4]);
        float4 x1 = *((const float4*)&xn[1][i4*4]);
        float4 x2 = *((const float4*)&xn[2][i4*4]);
        float4 x3 = *((const float4*)&xn[3][i4*4]);
        const float* p0 = (const float*)&x0;
        const float* p1 = (const float*)&x1;
        const float* p2 = (const float*)&x2;
        const float* p3 = (const float*)&x3;
        #pragma unroll
        for (int e = 0; e < 4; e++) {
            const int i = i4*4 + e;
            float wq = Wq[i*DIN + col], wk = Wk[i*DIN + col];
            float wvv = Wv[i*DIN + col], wg = Wg[i*DIN + col];
            aq[0] = fmaf(p0[e], wq, aq[0]); aq[1] = fmaf(p1[e], wq, aq[1]);
            aq[2] = fmaf(p2[e], wq, aq[2]); aq[3] = fmaf(p3[e], wq, aq[3]);
            ak[0] = fmaf(p0[e], wk, ak[0]); ak[1] = fmaf(p1[e], wk, ak[1]);
            ak[2] = fmaf(p2[e], wk, ak[2]); ak[3] = fmaf(p3[e], wk, ak[3]);
            av[0] = fmaf(p0[e], wvv, av[0]); av[1] = fmaf(p1[e], wvv, av[1]);
            av[2] = fmaf(p2[e], wvv, av[2]); av[3] = fmaf(p3[e], wvv, av[3]);
            ag[0] = fmaf(p0[e], wg, ag[0]); ag[1] = fmaf(p1[e], wg, ag[1]);
            ag[2] = fmaf(p2[e], wg, ag[2]); ag[3] = fmaf(p3[e], wg, ag[3]);
        }
    }
    const float kscale = 0.17677669529663687f;  // 1/sqrt(DH)
    float bgv = bg[col];
    #pragma unroll
    for (int r = 0; r < 4; r++) {
        const int orow = blockIdx.x*4 + r;
        qb[orow*DIN + col] = aq[r];
        kb[orow*DIN + col] = ak[r] * kscale;
        vb[orow*DIN + col] = av[r];
        gb[orow*DIN + col] = 1.0f/(1.0f + __expf(-(ag[r] + bgv)));
    }
}

// ---------------------------------------------------------------------------
// K2: qk pre-GEMM -> qkT[(q*LQ+k)*8+h]. Grid (24,24), 32x32 tile.
// ---------------------------------------------------------------------------
__global__ __launch_bounds__(256) void qk_kernel(
    const float* __restrict__ qb, const float* __restrict__ kb, float* __restrict__ qkT)
{
    __shared__ float q_l[32*260];
    __shared__ float k_l[32*260];
    const int tid = threadIdx.x;
    const int bq = blockIdx.x, bk = blockIdx.y;

    {
        const int row = tid >> 3, cg = tid & 7;
        const float4* qs = (const float4*)(qb + (size_t)(bq*32 + row)*DIN + cg*32);
        const float4* ks = (const float4*)(kb + (size_t)(bk*32 + row)*DIN + cg*32);
        #pragma unroll
        for (int j = 0; j < 8; j++) {
            *(float4*)&q_l[row*260 + cg*32 + j*4] = qs[j];
            *(float4*)&k_l[row*260 + cg*32 + j*4] = ks[j];
        }
    }
    __syncthreads();

    const int tx = tid & 15, ty = tid >> 4;
    float acc[2][2][NH];
    #pragma unroll
    for (int a = 0; a < 2; a++)
        #pragma unroll
        for (int b = 0; b < 2; b++)
            #pragma unroll
            for (int h = 0; h < NH; h++) acc[a][b][h] = 0.f;

    #pragma unroll
    for (int d4 = 0; d4 < 64; d4++) {
        const int h = d4 >> 3;
        float4 q0 = *(const float4*)&q_l[(ty*2+0)*260 + d4*4];
        float4 q1 = *(const float4*)&q_l[(ty*2+1)*260 + d4*4];
        float4 k0 = *(const float4*)&k_l[(tx*2+0)*260 + d4*4];
        float4 k1 = *(const float4*)&k_l[(tx*2+1)*260 + d4*4];
        acc[0][0][h] = fmaf(q0.x,k0.x,acc[0][0][h]); acc[0][0][h] = fmaf(q0.y,k0.y,acc[0][0][h]);
        acc[0][0][h] = fmaf(q0.z,k0.z,acc[0][0][h]); acc[0][0][h] = fmaf(q0.w,k0.w,acc[0][0][h]);
        acc[0][1][h] = fmaf(q0.x,k1.x,acc[0][1][h]); acc[0][1][h] = fmaf(q0.y,k1.y,acc[0][1][h]);
        acc[0][1][h] = fmaf(q0.z,k1.z,acc[0][1][h]); acc[0][1][h] = fmaf(q0.w,k1.w,acc[0][1][h]);
        acc[1][0][h] = fmaf(q1.x,k0.x,acc[1][0][h]); acc[1][0][h] = fmaf(q1.y,k0.y,acc[1][0][h]);
        acc[1][0][h] = fmaf(q1.z,k0.z,acc[1][0][h]); acc[1][0][h] = fmaf(q1.w,k0.w,acc[1][0][h]);
        acc[1][1][h] = fmaf(q1.x,k1.x,acc[1][1][h]); acc[1][1][h] = fmaf(q1.y,k1.y,acc[1][1][h]);
        acc[1][1][h] = fmaf(q1.z,k1.z,acc[1][1][h]); acc[1][1][h] = fmaf(q1.w,k1.w,acc[1][1][h]);
    }

    #pragma unroll
    for (int a = 0; a < 2; a++)
        #pragma unroll
        for (int b = 0; b < 2; b++) {
            size_t base = ((size_t)(bq*32 + ty*2 + a)*LQ + (bk*32 + tx*2 + b))*NH;
            *(float4*)(qkT + base)     = make_float4(acc[a][b][0], acc[a][b][1], acc[a][b][2], acc[a][b][3]);
            *(float4*)(qkT + base + 4) = make_float4(acc[a][b][4], acc[a][b][5], acc[a][b][6], acc[a][b][7]);
        }
}

// ---------------------------------------------------------------------------
// K3: bias stream, ONE THREAD PER KEY. Grid 2304 x 256 (block b: q=b/3,
// keys (b%3)*256+tid). Thread reads its key's 128 contiguous floats
// (32 x dwordx4; the 4 loads of each 64B-line group L1-hit), accumulates
// s/ss/acc[8] privately (NO shuffles, NO LDS, NO barriers), W2 via
// wave-uniform s_loads, adds precomputed qk, stores 8 logits.
// ---------------------------------------------------------------------------
__global__ __launch_bounds__(256, 6) void bias1t_kernel(
    const float* __restrict__ bias, const float* __restrict__ W2g,
    const float* __restrict__ SCg, const float* __restrict__ qkT,
    float* __restrict__ logits)
{
    const int bid = blockIdx.x;
    const int q   = bid / 3;
    const int key = (bid - q*3) * 256 + threadIdx.x;
    const size_t off = (size_t)q * LQ + key;

    const float4* src = (const float4*)(bias + off * DB);
    const float4* qkp = (const float4*)(qkT + off * NH);
    float4 qka = qkp[0];
    float4 qkb = qkp[1];

    float s = 0.f, ss = 0.f;
    float acc[NH] = {0,0,0,0,0,0,0,0};

    #pragma unroll
    for (int c = 0; c < 8; c++) {
        float4 b0 = src[c*4+0];
        float4 b1 = src[c*4+1];
        float4 b2 = src[c*4+2];
        float4 b3 = src[c*4+3];
        const float* wr = W2g + c*16*NH;          // uniform -> s_load
        #pragma unroll
        for (int e = 0; e < 4; e++) {
            float xv = (&b0.x)[e];
            s += xv; ss = fmaf(xv, xv, ss);
            #pragma unroll
            for (int h = 0; h < NH; h++) acc[h] = fmaf(xv, wr[e*NH+h], acc[h]);
        }
        #pragma unroll
        for (int e = 0; e < 4; e++) {
            float xv = (&b1.x)[e];
            s += xv; ss = fmaf(xv, xv, ss);
            #pragma unroll
            for (int h = 0; h < NH; h++) acc[h] = fmaf(xv, wr[(4+e)*NH+h], acc[h]);
        }
        #pragma unroll
        for (int e = 0; e < 4; e++) {
            float xv = (&b2.x)[e];
            s += xv; ss = fmaf(xv, xv, ss);
            #pragma unroll
            for (int h = 0; h < NH; h++) acc[h] = fmaf(xv, wr[(8+e)*NH+h], acc[h]);
        }
        #pragma unroll
        for (int e = 0; e < 4; e++) {
            float xv = (&b3.x)[e];
            s += xv; ss = fmaf(xv, xv, ss);
            #pragma unroll
            for (int h = 0; h < NH; h++) acc[h] = fmaf(xv, wr[(12+e)*NH+h], acc[h]);
        }
    }

    float mu  = s * (1.0f/DB);
    float inv = rsqrtf(ss * (1.0f/DB) - mu*mu + 1e-5f);
    float lo[NH];
    #pragma unroll
    for (int h = 0; h < NH; h++)
        lo[h] = fmaf(inv, fmaf(-mu, SCg[h], acc[h]), SCg[NH+h]);
    lo[0] += qka.x; lo[1] += qka.y; lo[2] += qka.z; lo[3] += qka.w;
    lo[4] += qkb.x; lo[5] += qkb.y; lo[6] += qkb.z; lo[7] += qkb.w;

    float4* dst = (float4*)(logits + off * NH);
    dst[0] = make_float4(lo[0], lo[1], lo[2], lo[3]);
    dst[1] = make_float4(lo[4], lo[5], lo[6], lo[7]);
}

// ---------------------------------------------------------------------------
// K4: attn tail: logits (qk already included) -> softmax, PV, gate, Wo.
// 2 q-rows per block, grid 384.
// ---------------------------------------------------------------------------
__global__ __launch_bounds__(256) void attn_kernel(
    const float* __restrict__ logits, const float* __restrict__ vbuf,
    const float* __restrict__ gb, const float* __restrict__ Wo,
    const float* __restrict__ bo, float* __restrict__ out)
{
    const int tid = threadIdx.x;
    const int q0 = blockIdx.x * 2;
    __shared__ float pT[2][NH][776];
    __shared__ float ao[2][DIN];
    __shared__ float isum[2][NH];

    #pragma unroll
    for (int r = 0; r < 2; r++) {
        const float4* rp = (const float4*)(logits + (size_t)(q0 + r)*LQ*NH);
        #pragma unroll
        for (int ii = 0; ii < 6; ii++) {
            int jj = ii*256 + tid;
            float4 t = rp[jj];
            int k = jj >> 1, h0 = (jj & 1) << 2;
            pT[r][h0+0][k] = t.x; pT[r][h0+1][k] = t.y;
            pT[r][h0+2][k] = t.z; pT[r][h0+3][k] = t.w;
        }
    }
    __syncthreads();

    {
        const int r = tid >> 7, h = (tid >> 4) & 7, l = tid & 15;
        float4* row = (float4*)&pT[r][h][0];
        float m = -1e30f;
        for (int i = l; i < 192; i += 16) {
            float4 v = row[i];
            m = fmaxf(m, fmaxf(fmaxf(v.x, v.y), fmaxf(v.z, v.w)));
        }
        #pragma unroll
        for (int mm = 1; mm <= 8; mm <<= 1) m = fmaxf(m, __shfl_xor(m, mm));
        float sum = 0.f;
        for (int i = l; i < 192; i += 16) {
            float4 v = row[i];
            v.x = __expf(v.x - m); v.y = __expf(v.y - m);
            v.z = __expf(v.z - m); v.w = __expf(v.w - m);
            sum += v.x + v.y + v.z + v.w;
            row[i] = v;
        }
        #pragma unroll
        for (int mm = 1; mm <= 8; mm <<= 1) sum += __shfl_xor(sum, mm);
        if (l == 0) isum[r][h] = 1.0f / sum;
    }
    __syncthreads();

    {
        const int h = tid >> 5, d = tid & 31;
        const float* vp = vbuf + h*DH + d;
        const float4* p0r = (const float4*)&pT[0][h][0];
        const float4* p1r = (const float4*)&pT[1][h][0];
        float a0 = 0.f, a1 = 0.f;
        for (int k4 = 0; k4 < 192; k4++) {
            float4 p0 = p0r[k4], p1 = p1r[k4];
            float v0 = vp[(size_t)(k4*4+0)*DIN];
            float v1 = vp[(size_t)(k4*4+1)*DIN];
            float v2 = vp[(size_t)(k4*4+2)*DIN];
            float v3 = vp[(size_t)(k4*4+3)*DIN];
            a0 = fmaf(p0.x, v0, a0); a0 = fmaf(p0.y, v1, a0);
            a0 = fmaf(p0.z, v2, a0); a0 = fmaf(p0.w, v3, a0);
            a1 = fmaf(p1.x, v0, a1); a1 = fmaf(p1.y, v1, a1);
            a1 = fmaf(p1.z, v2, a1); a1 = fmaf(p1.w, v3, a1);
        }
        ao[0][tid] = a0 * isum[0][h] * gb[(q0+0)*DIN + tid];
        ao[1][tid] = a1 * isum[1][h] * gb[(q0+1)*DIN + tid];
    }
    __syncthreads();

    {
        const int col = tid;
        float o0 = bo[col], o1 = o0;
        for (int i = 0; i < DIN; i++) {
            float wv = Wo[i*DIN + col];
            o0 = fmaf(ao[0][i], wv, o0);
            o1 = fmaf(ao[1][i], wv, o1);
        }
        out[(q0+0)*DIN + col] = o0;
        out[(q0+1)*DIN + col] = o1;
    }
}

extern "C" void kernel_launch(void* const* d_in, const int* in_sizes, int n_in,
                              void* d_out, int out_size, void* d_ws, size_t ws_size,
                              hipStream_t stream) {
    const float* x    = (const float*)d_in[0];
    const float* bias = (const float*)d_in[1];
    const float* lnw  = (const float*)d_in[2];
    const float* lnb  = (const float*)d_in[3];
    const float* lbw  = (const float*)d_in[4];
    const float* lbb  = (const float*)d_in[5];
    const float* Wq   = (const float*)d_in[6];
    const float* Wk   = (const float*)d_in[7];
    const float* Wv   = (const float*)d_in[8];
    const float* Wb   = (const float*)d_in[9];
    const float* Wg   = (const float*)d_in[10];
    const float* bg   = (const float*)d_in[11];
    const float* Wo   = (const float*)d_in[12];
    const float* bo   = (const float*)d_in[13];

    float* ws = (float*)d_ws;
    float* qb = ws + OFF_QB;
    float* kb = ws + OFF_KB;
    float* vb = ws + OFF_VB;
    float* gb = ws + OFF_GB;
    float* W2 = ws + OFF_W2;
    float* SC = ws + OFF_SC;
    float* qk = ws + OFF_QK;
    float* lg = ws + OFF_LG;

    projsetup_kernel<<<193, 256, 0, stream>>>(x, lnw, lnb, Wq, Wk, Wv, Wg, bg,
                                              lbw, lbb, Wb, qb, kb, vb, gb, W2, SC);
    qk_kernel<<<dim3(24, 24), 256, 0, stream>>>(qb, kb, qk);
    bias1t_kernel<<<2304, 256, 0, stream>>>(bias, W2, SC, qk, lg);
    attn_kernel<<<LQ/2, 256, 0, stream>>>(lg, vb, gb, Wo, bo, (float*)d_out);
}